// Round 27
// baseline (88.570 us; speedup 1.0000x reference)
//
#include <hip/hip_runtime.h>
#include <math.h>

#define DIM 256
#define KCODES 1024
#define NTILE 64   // 16-code tiles (2KB fp4 each)
#define BM 256     // rows per block (4 waves x 64 rows)
#define EB 4096.0f             // codebook scale: e*4096 in (-4,4) fp4 range
#define UNIT_SCALE 0x7F7F7F7F  // E8M0 127 = 2^0 in every byte

typedef __attribute__((ext_vector_type(8))) int i32x8;
typedef __attribute__((ext_vector_type(4))) int i32x4;
typedef __attribute__((ext_vector_type(4))) float f32x4;

// fp4 e2m1 quantizer (round to nearest on {0,.5,1,1.5,2,3,4,6})
__device__ inline unsigned fp4q(float v) {
  const float a = fabsf(v);
  const unsigned s = (v < 0.0f) ? 8u : 0u;
  unsigned m;
  if (a < 0.25f) m = 0;
  else if (a < 0.75f) m = 1;
  else if (a < 1.25f) m = 2;
  else if (a < 1.75f) m = 3;
  else if (a < 2.5f) m = 4;
  else if (a < 3.5f) m = 5;
  else if (a < 5.0f) m = 6;
  else m = 7;
  return s | m;
}

// ---------------------------------------------------------------------------
// Prep: enormh[k] = -EB*||e_k||^2/2, codebook scaled x4096 -> fp4 e2m1 in
// MFMA B-fragment order (16B/lane/K-half):
// byte = (k>>4)*2048 + (d>>7)*1024 + (((d>>5)&3)*16 + (k&15))*16 + ((d&31)>>1)
// ---------------------------------------------------------------------------
__global__ __launch_bounds__(64) void vq_prep_kernel(
    const float* __restrict__ E, float* __restrict__ enormh,
    unsigned char* __restrict__ Ef4) {
  const int k = blockIdx.x;   // code
  const int t = threadIdx.x;  // dims 4t..4t+3
  const float4 v = *reinterpret_cast<const float4*>(&E[k * DIM + t * 4]);
  const int d0 = t * 4;
  const size_t byte = (size_t)((k >> 4) * 2048) + (size_t)((d0 >> 7) * 1024) +
                      (size_t)(((((d0 >> 5) & 3) * 16) + (k & 15)) * 16) +
                      (size_t)((d0 & 31) >> 1);
  const unsigned n0 = fp4q(v.x * EB), n1 = fp4q(v.y * EB);
  const unsigned n2 = fp4q(v.z * EB), n3 = fp4q(v.w * EB);
  const unsigned short pk =
      (unsigned short)(n0 | (n1 << 4) | (n2 << 8) | (n3 << 12));
  *reinterpret_cast<unsigned short*>(Ef4 + byte) = pk;
  float s = v.x * v.x + v.y * v.y + v.z * v.z + v.w * v.w;
#pragma unroll
  for (int off = 32; off >= 1; off >>= 1) s += __shfl_down(s, off);
  if (t == 0) enormh[k] = -0.5f * EB * s;
}

// ---------------------------------------------------------------------------
// Fused main v27: v26's barrier-free fp4 MX register pipeline at 64 ROWS
// PER WAVE (v15 geometry, rehabilitated by fp4's small register footprint).
// 256 rows/block, 256 thr = 4 waves x 64 rows; grid 256 = 1 block/CU.
// Total B L2-traffic halves to 128 MB. Per tile: 8 MFMAs in 4 interleaved
// acc chains (~250cyc) -> 4-deep ring window ~875cyc >> L2 latency; latency
// covered by ILP-window, not TLP (1 wave/SIMD).
// ---------------------------------------------------------------------------
__global__ __launch_bounds__(256, 1) void vq_fused_kernel(
    const float* __restrict__ X, const float* __restrict__ E,
    const unsigned char* __restrict__ Ef4, const float* __restrict__ enormh,
    float* __restrict__ outq, float* __restrict__ partials) {
  __shared__ int idxs[BM];
  __shared__ float lred[4];

  const int tid = threadIdx.x;
  const int w = tid >> 6;  // wave 0..3 -> rows w*64 .. w*64+63
  const int lane = tid & 63;
  const int lr = lane & 15;
  const int lk = lane >> 4;
  const int row0 = blockIdx.x * BM;

  // ---- A: 64 rows x 256 dims per wave -> fp8 fragments for 16x16x128
  // (lane: row = mt*16+lr, k = lk*32 + j within K-half ks2). 64 VGPRs.
  i32x8 Af[4][2];
  float xsq = 0.0f;
#pragma unroll
  for (int mt = 0; mt < 4; ++mt) {
    const float* xrow = &X[(size_t)(row0 + w * 64 + mt * 16 + lr) * DIM];
#pragma unroll
    for (int ks2 = 0; ks2 < 2; ++ks2) {
      const int k0 = ks2 * 128 + lk * 32;
      i32x8 af;
#pragma unroll
      for (int p = 0; p < 8; ++p) {
        const float4 a = *reinterpret_cast<const float4*>(&xrow[k0 + p * 4]);
        xsq += a.x * a.x + a.y * a.y + a.z * a.z + a.w * a.w;
        int pk = __builtin_amdgcn_cvt_pk_fp8_f32(a.x, a.y, 0, 0);
        pk = __builtin_amdgcn_cvt_pk_fp8_f32(a.z, a.w, pk, 1);
        af[p] = pk;
      }
      Af[mt][ks2] = af;
    }
  }

  float maxv[16];
  int mini[16];
#pragma unroll
  for (int i = 0; i < 16; ++i) { maxv[i] = -INFINITY; mini[i] = 0; }

  const char* efbase = reinterpret_cast<const char*>(Ef4) + lane * 16;

  // ---- 4-deep named register ring (static-indexed via full unroll)
  i32x4 Ba[4], Bb[4];
  float en[4];
#pragma unroll
  for (int s = 0; s < 4; ++s) {
    Ba[s] = *reinterpret_cast<const i32x4*>(efbase + (size_t)s * 2048);
    Bb[s] = *reinterpret_cast<const i32x4*>(efbase + (size_t)s * 2048 + 1024);
    en[s] = enormh[s * 16 + lr];
  }

#pragma unroll
  for (int t = 0; t < NTILE; ++t) {
    const int sl = t & 3;
    f32x4 acc[4];
#pragma unroll
    for (int mt = 0; mt < 4; ++mt) {
      acc[mt][0] = en[sl]; acc[mt][1] = en[sl];
      acc[mt][2] = en[sl]; acc[mt][3] = en[sl];
    }
    {
      i32x8 ba8 = {}, bb8 = {};
      ba8[0] = Ba[sl][0]; ba8[1] = Ba[sl][1];
      ba8[2] = Ba[sl][2]; ba8[3] = Ba[sl][3];
      bb8[0] = Bb[sl][0]; bb8[1] = Bb[sl][1];
      bb8[2] = Bb[sl][2]; bb8[3] = Bb[sl][3];
      // 8 MFMAs: 4 interleaved acc chains x 2 K-halves (dep distance 4)
#pragma unroll
      for (int mt = 0; mt < 4; ++mt)
        acc[mt] = __builtin_amdgcn_mfma_scale_f32_16x16x128_f8f6f4(
            Af[mt][0], ba8, acc[mt], 0, 4, 0, UNIT_SCALE, 0, UNIT_SCALE);
#pragma unroll
      for (int mt = 0; mt < 4; ++mt)
        acc[mt] = __builtin_amdgcn_mfma_scale_f32_16x16x128_f8f6f4(
            Af[mt][1], bb8, acc[mt], 0, 4, 0, UNIT_SCALE, 0, UNIT_SCALE);
    }
    if (t + 4 < NTILE) {
      const char* nsrc = efbase + (size_t)(t + 4) * 2048;
      Ba[sl] = *reinterpret_cast<const i32x4*>(nsrc);
      Bb[sl] = *reinterpret_cast<const i32x4*>(nsrc + 1024);
      en[sl] = enormh[(t + 4) * 16 + lr];
    }
    const int code = t * 16 + lr;  // ascending per lane -> first occurrence
#pragma unroll
    for (int mt = 0; mt < 4; ++mt)
#pragma unroll
      for (int r = 0; r < 4; ++r) {
        const int ri = mt * 4 + r;  // row w*64 + mt*16 + lk*4 + r
        if (acc[mt][r] > maxv[ri]) { maxv[ri] = acc[mt][r]; mini[ri] = code; }
      }
  }

  // reduce across the 16 code-lanes (lr); max score, tie -> lower code
#pragma unroll
  for (int off = 1; off < 16; off <<= 1) {
#pragma unroll
    for (int ri = 0; ri < 16; ++ri) {
      const float ov = __shfl_xor(maxv[ri], off);
      const int oi = __shfl_xor(mini[ri], off);
      if (ov > maxv[ri] || (ov == maxv[ri] && oi < mini[ri])) {
        maxv[ri] = ov; mini[ri] = oi;
      }
    }
  }
  if (lr == 0) {
#pragma unroll
    for (int mt = 0; mt < 4; ++mt)
#pragma unroll
      for (int r = 0; r < 4; ++r)
        idxs[w * 64 + mt * 16 + lk * 4 + r] = mini[mt * 4 + r];
  }

  // ---- loss partial from registers: Sum(x^2) + (-2/EB)*Sum(maxv_sel)
  float lsum = xsq;
  if (lr == 0) {
    float ssum = 0.0f;
#pragma unroll
    for (int ri = 0; ri < 16; ++ri) ssum += maxv[ri];
    lsum += ssum * (-2.0f / EB);
  }
#pragma unroll
  for (int off = 32; off >= 1; off >>= 1) lsum += __shfl_down(lsum, off);
  if (lane == 0) lred[w] = lsum;
  __syncthreads();

  // ---- epilogue: outq row = E[code] (pure L2 gather -> coalesced write).
#pragma unroll
  for (int q = 0; q < 4; ++q) {
    const int er = q * 64 + (tid >> 2);
    const int eq = tid & 3;
    const int code = idxs[er];
    const float* erow = &E[(size_t)code * DIM];
    float* orow = &outq[(size_t)(row0 + er) * DIM];
#pragma unroll
    for (int j = 0; j < 16; ++j) {
      const int d = j * 16 + eq * 4;
      *reinterpret_cast<float4*>(&orow[d]) =
          *reinterpret_cast<const float4*>(&erow[d]);
    }
  }
  if (tid == 0)
    partials[blockIdx.x] = lred[0] + lred[1] + lred[2] + lred[3];
}

// ---------------------------------------------------------------------------
// Deterministic loss reduction: loss = 1.25 * Sum(e-x)^2 / N
// ---------------------------------------------------------------------------
__global__ __launch_bounds__(256) void vq_finalize_kernel(
    const float* __restrict__ partials, float* __restrict__ out_loss,
    int nparts, float inv_count) {
  const int tid = threadIdx.x;
  float s = 0.0f;
  for (int i = tid; i < nparts; i += 256) s += partials[i];
#pragma unroll
  for (int off = 32; off >= 1; off >>= 1) s += __shfl_down(s, off);
  __shared__ float w[4];
  if ((tid & 63) == 0) w[tid >> 6] = s;
  __syncthreads();
  if (tid == 0)
    out_loss[0] = 1.25f * (w[0] + w[1] + w[2] + w[3]) * inv_count;
}

extern "C" void kernel_launch(void* const* d_in, const int* in_sizes, int n_in,
                              void* d_out, int out_size, void* d_ws,
                              size_t ws_size, hipStream_t stream) {
  const float* X = (const float*)d_in[0];  // [16,4096,256] fp32
  const float* E = (const float*)d_in[1];  // [1024,256] fp32
  float* out = (float*)d_out;              // [0]=loss, [1..]=quantized

  char* ws = (char*)d_ws;
  float* enormh = (float*)ws;                             // @0KB
  float* partials = (float*)(ws + 16 * 1024);             // @16KB
  unsigned char* Ef4 = (unsigned char*)(ws + 48 * 1024);  // @48KB (128KB)

  const int nrows = in_sizes[0] / DIM;  // 65536
  const int nb_main = nrows / BM;       // 256

  vq_prep_kernel<<<KCODES, 64, 0, stream>>>(E, enormh, Ef4);
  vq_fused_kernel<<<nb_main, 256, 0, stream>>>(X, E, Ef4, enormh, out + 1,
                                               partials);
  vq_finalize_kernel<<<1, 256, 0, stream>>>(partials, out, nb_main,
                                            1.0f / (float)in_sizes[0]);
}

// Round 28
// 50.263 us; speedup vs baseline: 1.7621x; 1.7621x over previous
//
#include <hip/hip_runtime.h>
#include <math.h>

#define DIM 256
#define KCODES 1024
#define NTILE 64   // 16-code tiles (2KB fp4 each)
#define BM 128     // rows per block (4 waves x 32 rows)
#define EB 4096.0f             // codebook scale: e*4096 in (-4,4) fp4 range
#define UNIT_SCALE 0x7F7F7F7F  // E8M0 127 = 2^0 in every byte

typedef __attribute__((ext_vector_type(8))) int i32x8;
typedef __attribute__((ext_vector_type(4))) int i32x4;
typedef __attribute__((ext_vector_type(4))) float f32x4;

// fp4 e2m1 quantizer (round to nearest on {0,.5,1,1.5,2,3,4,6})
__device__ inline unsigned fp4q(float v) {
  const float a = fabsf(v);
  const unsigned s = (v < 0.0f) ? 8u : 0u;
  unsigned m;
  if (a < 0.25f) m = 0;
  else if (a < 0.75f) m = 1;
  else if (a < 1.25f) m = 2;
  else if (a < 1.75f) m = 3;
  else if (a < 2.5f) m = 4;
  else if (a < 3.5f) m = 5;
  else if (a < 5.0f) m = 6;
  else m = 7;
  return s | m;
}

// ---------------------------------------------------------------------------
// Prep: enormh[k] = -EB*||e_k||^2/2, codebook scaled x4096 -> fp4 e2m1 in
// MFMA B-fragment order (16B/lane/K-half):
// byte = (k>>4)*2048 + (d>>7)*1024 + (((d>>5)&3)*16 + (k&15))*16 + ((d&31)>>1)
// ---------------------------------------------------------------------------
__global__ __launch_bounds__(64) void vq_prep_kernel(
    const float* __restrict__ E, float* __restrict__ enormh,
    unsigned char* __restrict__ Ef4) {
  const int k = blockIdx.x;   // code
  const int t = threadIdx.x;  // dims 4t..4t+3
  const float4 v = *reinterpret_cast<const float4*>(&E[k * DIM + t * 4]);
  const int d0 = t * 4;
  const size_t byte = (size_t)((k >> 4) * 2048) + (size_t)((d0 >> 7) * 1024) +
                      (size_t)(((((d0 >> 5) & 3) * 16) + (k & 15)) * 16) +
                      (size_t)((d0 & 31) >> 1);
  const unsigned n0 = fp4q(v.x * EB), n1 = fp4q(v.y * EB);
  const unsigned n2 = fp4q(v.z * EB), n3 = fp4q(v.w * EB);
  const unsigned short pk =
      (unsigned short)(n0 | (n1 << 4) | (n2 << 8) | (n3 << 12));
  *reinterpret_cast<unsigned short*>(Ef4 + byte) = pk;
  float s = v.x * v.x + v.y * v.y + v.z * v.z + v.w * v.w;
#pragma unroll
  for (int off = 32; off >= 1; off >>= 1) s += __shfl_down(s, off);
  if (t == 0) enormh[k] = -0.5f * EB * s;
}

// ---------------------------------------------------------------------------
// Fused main v28 (= v26, the measured best): barrier-free fp4 MX register
// pipeline, 32 rows/wave, 4-deep register ring, separate finalize kernel.
// 128 rows/block, 256 thr = 4 independent waves; wave w owns rows
// [w*32,w*32+32) x ALL 1024 codes. No LDS hot loop, no atomics, no fences.
// Loss computed algebraically from registers; epilogue = pure E-gather.
// ---------------------------------------------------------------------------
__global__ __launch_bounds__(256, 2) void vq_fused_kernel(
    const float* __restrict__ X, const float* __restrict__ E,
    const unsigned char* __restrict__ Ef4, const float* __restrict__ enormh,
    float* __restrict__ outq, float* __restrict__ partials) {
  __shared__ int idxs[BM];
  __shared__ float lred[4];

  const int tid = threadIdx.x;
  const int w = tid >> 6;  // wave 0..3 -> rows w*32 .. w*32+31
  const int lane = tid & 63;
  const int lr = lane & 15;
  const int lk = lane >> 4;
  const int row0 = blockIdx.x * BM;

  // ---- A: 32 rows x 256 dims per wave -> fp8 fragments for 16x16x128
  i32x8 Af[2][2];
  float xsq = 0.0f;
#pragma unroll
  for (int mt = 0; mt < 2; ++mt) {
    const float* xrow = &X[(size_t)(row0 + w * 32 + mt * 16 + lr) * DIM];
#pragma unroll
    for (int ks2 = 0; ks2 < 2; ++ks2) {
      const int k0 = ks2 * 128 + lk * 32;
      i32x8 af;
#pragma unroll
      for (int p = 0; p < 8; ++p) {
        const float4 a = *reinterpret_cast<const float4*>(&xrow[k0 + p * 4]);
        xsq += a.x * a.x + a.y * a.y + a.z * a.z + a.w * a.w;
        int pk = __builtin_amdgcn_cvt_pk_fp8_f32(a.x, a.y, 0, 0);
        pk = __builtin_amdgcn_cvt_pk_fp8_f32(a.z, a.w, pk, 1);
        af[p] = pk;
      }
      Af[mt][ks2] = af;
    }
  }

  float maxv[8];
  int mini[8];
#pragma unroll
  for (int i = 0; i < 8; ++i) { maxv[i] = -INFINITY; mini[i] = 0; }

  const char* efbase = reinterpret_cast<const char*>(Ef4) + lane * 16;

  // ---- 4-deep named register ring (static-indexed via full unroll)
  i32x4 Ba[4], Bb[4];
  float en[4];
#pragma unroll
  for (int s = 0; s < 4; ++s) {
    Ba[s] = *reinterpret_cast<const i32x4*>(efbase + (size_t)s * 2048);
    Bb[s] = *reinterpret_cast<const i32x4*>(efbase + (size_t)s * 2048 + 1024);
    en[s] = enormh[s * 16 + lr];
  }

#pragma unroll
  for (int t = 0; t < NTILE; ++t) {
    const int sl = t & 3;
    f32x4 acc0, acc1;
    acc0[0] = en[sl]; acc0[1] = en[sl]; acc0[2] = en[sl]; acc0[3] = en[sl];
    acc1 = acc0;
    {
      i32x8 ba8 = {}, bb8 = {};
      ba8[0] = Ba[sl][0]; ba8[1] = Ba[sl][1];
      ba8[2] = Ba[sl][2]; ba8[3] = Ba[sl][3];
      bb8[0] = Bb[sl][0]; bb8[1] = Bb[sl][1];
      bb8[2] = Bb[sl][2]; bb8[3] = Bb[sl][3];
      acc0 = __builtin_amdgcn_mfma_scale_f32_16x16x128_f8f6f4(
          Af[0][0], ba8, acc0, 0, 4, 0, UNIT_SCALE, 0, UNIT_SCALE);
      acc1 = __builtin_amdgcn_mfma_scale_f32_16x16x128_f8f6f4(
          Af[1][0], ba8, acc1, 0, 4, 0, UNIT_SCALE, 0, UNIT_SCALE);
      acc0 = __builtin_amdgcn_mfma_scale_f32_16x16x128_f8f6f4(
          Af[0][1], bb8, acc0, 0, 4, 0, UNIT_SCALE, 0, UNIT_SCALE);
      acc1 = __builtin_amdgcn_mfma_scale_f32_16x16x128_f8f6f4(
          Af[1][1], bb8, acc1, 0, 4, 0, UNIT_SCALE, 0, UNIT_SCALE);
    }
    if (t + 4 < NTILE) {
      const char* nsrc = efbase + (size_t)(t + 4) * 2048;
      Ba[sl] = *reinterpret_cast<const i32x4*>(nsrc);
      Bb[sl] = *reinterpret_cast<const i32x4*>(nsrc + 1024);
      en[sl] = enormh[(t + 4) * 16 + lr];
    }
    const int code = t * 16 + lr;  // ascending per lane -> first occurrence
#pragma unroll
    for (int r = 0; r < 4; ++r) {
      if (acc0[r] > maxv[r]) { maxv[r] = acc0[r]; mini[r] = code; }
      if (acc1[r] > maxv[4 + r]) { maxv[4 + r] = acc1[r]; mini[4 + r] = code; }
    }
  }

  // reduce across the 16 code-lanes (lr); max score, tie -> lower code
#pragma unroll
  for (int off = 1; off < 16; off <<= 1) {
#pragma unroll
    for (int ri = 0; ri < 8; ++ri) {
      const float ov = __shfl_xor(maxv[ri], off);
      const int oi = __shfl_xor(mini[ri], off);
      if (ov > maxv[ri] || (ov == maxv[ri] && oi < mini[ri])) {
        maxv[ri] = ov; mini[ri] = oi;
      }
    }
  }
  if (lr == 0) {
#pragma unroll
    for (int mt = 0; mt < 2; ++mt)
#pragma unroll
      for (int r = 0; r < 4; ++r)
        idxs[w * 32 + mt * 16 + lk * 4 + r] = mini[mt * 4 + r];
  }

  // ---- loss partial from registers: Sum(x^2) + (-2/EB)*Sum(maxv_sel)
  float lsum = xsq;
  if (lr == 0) {
    float ssum = 0.0f;
#pragma unroll
    for (int ri = 0; ri < 8; ++ri) ssum += maxv[ri];
    lsum += ssum * (-2.0f / EB);
  }
#pragma unroll
  for (int off = 32; off >= 1; off >>= 1) lsum += __shfl_down(lsum, off);
  if (lane == 0) lred[w] = lsum;
  __syncthreads();

  // ---- epilogue: outq row = E[code] (pure L2 gather -> coalesced write).
#pragma unroll
  for (int half = 0; half < 2; ++half) {
    const int er = half * 64 + (tid >> 2);
    const int eq = tid & 3;
    const int code = idxs[er];
    const float* erow = &E[(size_t)code * DIM];
    float* orow = &outq[(size_t)(row0 + er) * DIM];
#pragma unroll
    for (int j = 0; j < 16; ++j) {
      const int d = j * 16 + eq * 4;
      *reinterpret_cast<float4*>(&orow[d]) =
          *reinterpret_cast<const float4*>(&erow[d]);
    }
  }
  if (tid == 0)
    partials[blockIdx.x] = lred[0] + lred[1] + lred[2] + lred[3];
}

// ---------------------------------------------------------------------------
// Deterministic loss reduction: loss = 1.25 * Sum(e-x)^2 / N
// ---------------------------------------------------------------------------
__global__ __launch_bounds__(256) void vq_finalize_kernel(
    const float* __restrict__ partials, float* __restrict__ out_loss,
    int nparts, float inv_count) {
  const int tid = threadIdx.x;
  float s = 0.0f;
  for (int i = tid; i < nparts; i += 256) s += partials[i];
#pragma unroll
  for (int off = 32; off >= 1; off >>= 1) s += __shfl_down(s, off);
  __shared__ float w[4];
  if ((tid & 63) == 0) w[tid >> 6] = s;
  __syncthreads();
  if (tid == 0)
    out_loss[0] = 1.25f * (w[0] + w[1] + w[2] + w[3]) * inv_count;
}

extern "C" void kernel_launch(void* const* d_in, const int* in_sizes, int n_in,
                              void* d_out, int out_size, void* d_ws,
                              size_t ws_size, hipStream_t stream) {
  const float* X = (const float*)d_in[0];  // [16,4096,256] fp32
  const float* E = (const float*)d_in[1];  // [1024,256] fp32
  float* out = (float*)d_out;              // [0]=loss, [1..]=quantized

  char* ws = (char*)d_ws;
  float* enormh = (float*)ws;                             // @0KB
  float* partials = (float*)(ws + 16 * 1024);             // @16KB
  unsigned char* Ef4 = (unsigned char*)(ws + 48 * 1024);  // @48KB (128KB)

  const int nrows = in_sizes[0] / DIM;  // 65536
  const int nb_main = nrows / BM;       // 512

  vq_prep_kernel<<<KCODES, 64, 0, stream>>>(E, enormh, Ef4);
  vq_fused_kernel<<<nb_main, 256, 0, stream>>>(X, E, Ef4, enormh, out + 1,
                                               partials);
  vq_finalize_kernel<<<1, 256, 0, stream>>>(partials, out, nb_main,
                                            1.0f / (float)in_sizes[0]);
}